// Round 14
// baseline (176.713 us; speedup 1.0000x reference)
//
#include <hip/hip_runtime.h>
#include <math.h>

#define N_NODES 20000
#define N_EDGES 640000
#define CAP 96        // bucket capacity: deg ~ Binom(640k,1/20k), mean 32, +11 sigma

// ---------------------------------------------------------------------------
// compose_zero: (blocks 0..32) fold post-aggregation linears into projections;
// (blocks 33..111) zero the cnt array.
//   P1 = w_rel1 @ w_l1 ; Q1 = w_root1 @ w_l1 ; c1 = b_rel1 @ w_l1 + b_l1
//   W2r = w_rel2 @ w_l2 ; W2o = w_root2 @ w_l2 ; c2 = b_rel2 @ w_l2 + b_l2
// ---------------------------------------------------------------------------
__global__ __launch_bounds__(256) void compose_zero(
    const float* __restrict__ w_rel1, const float* __restrict__ b_rel1,
    const float* __restrict__ w_root1,
    const float* __restrict__ w_l1, const float* __restrict__ b_l1,
    const float* __restrict__ w_rel2, const float* __restrict__ b_rel2,
    const float* __restrict__ w_root2,
    const float* __restrict__ w_l2, const float* __restrict__ b_l2,
    float* __restrict__ P1, float* __restrict__ Q1, float* __restrict__ c1,
    float* __restrict__ W2r, float* __restrict__ W2o, float* __restrict__ c2,
    int* __restrict__ cnt)
{
    const int b = blockIdx.x, t = threadIdx.x;
    if (b < 32) {
        const bool isP = (b < 16);
        const int idx = (isP ? b : b - 16) * 256 + t;   // 0..4095
        const int k = idx >> 5, j = idx & 31;
        const float* wsrc = isP ? w_rel1 : w_root1;
        float s = 0.f;
        #pragma unroll 8
        for (int m = 0; m < 64; ++m) s += wsrc[k * 64 + m] * w_l1[m * 32 + j];
        (isP ? P1 : Q1)[idx] = s;
    } else if (b == 32) {
        for (int i = t; i < 512; i += 256) {
            const int k = i >> 4, j = i & 15;
            float sr = 0.f, so = 0.f;
            if (j < 10) {
                #pragma unroll
                for (int m = 0; m < 16; ++m) {
                    sr += w_rel2[k * 16 + m] * w_l2[m * 10 + j];
                    so += w_root2[k * 16 + m] * w_l2[m * 10 + j];
                }
            }
            W2r[i] = sr;
            W2o[i] = so;
        }
        if (t < 32) {
            float s = b_l1[t];
            #pragma unroll 8
            for (int m = 0; m < 64; ++m) s += b_rel1[m] * w_l1[m * 32 + t];
            c1[t] = s;
        }
        if (t < 16) {
            float s = 0.f;
            if (t < 10) {
                s = b_l2[t];
                #pragma unroll
                for (int m = 0; m < 16; ++m) s += b_rel2[m] * w_l2[m * 10 + t];
            }
            c2[t] = s;
        }
    } else {
        const int i = (b - 33) * 256 + t;
        if (i < N_NODES) cnt[i] = 0;
    }
}

// ---------------------------------------------------------------------------
// fill_bucket: 1 edge/thread, 2500 blocks (max TLP — round-13 showed the
// load->atomic->store chain is latency-bound; round-8 showed more edges/thread
// HURT). Loads are lane-consecutive dwords (perfectly coalesced).
// ---------------------------------------------------------------------------
__global__ __launch_bounds__(256) void fill_bucket(
    const int* __restrict__ ei, int* __restrict__ cnt,
    int* __restrict__ esrc)
{
    const int e = blockIdx.x * 256 + threadIdx.x;   // 2500*256 = 640000 exact
    const int s = ei[e];
    const int d = ei[N_EDGES + e];
    const int p = atomicAdd(&cnt[d], 1);
    if (p < CAP) esrc[d * CAP + p] = s;
}

// ---------------------------------------------------------------------------
// proj1: a = x @ P1 [N,32] ; r = x @ Q1 + c1 [N,32]   (round-12 verified form)
// ---------------------------------------------------------------------------
__global__ __launch_bounds__(256) void proj1(
    const float* __restrict__ x, const float* __restrict__ P1,
    const float* __restrict__ Q1, const float* __restrict__ c1,
    float* __restrict__ a, float* __restrict__ r)
{
    __shared__ float s_W[128 * 64];
    for (int i = threadIdx.x; i < 128 * 64; i += 256) {
        const int k = i >> 6, j = i & 63;
        s_W[i] = (j < 32) ? P1[k * 32 + j] : Q1[k * 32 + (j - 32)];
    }
    __syncthreads();

    const int wave = threadIdx.x >> 6;
    const int lane = threadIdx.x & 63;
    const int f = lane & 31;
    const float cadd = (lane >= 32) ? c1[f] : 0.f;

    const int n0 = blockIdx.x * 16 + wave * 4;   // grid 1250 -> exactly 20000
    const float4* xp0 = (const float4*)(x + (n0 + 0) * 128);
    const float4* xp1 = (const float4*)(x + (n0 + 1) * 128);
    const float4* xp2 = (const float4*)(x + (n0 + 2) * 128);
    const float4* xp3 = (const float4*)(x + (n0 + 3) * 128);
    float a0 = 0.f, a1 = 0.f, a2 = 0.f, a3 = 0.f;
    #pragma unroll 8
    for (int k4 = 0; k4 < 32; ++k4) {
        const float4 va = xp0[k4], vb = xp1[k4], vc = xp2[k4], vd = xp3[k4];
        const int kb = k4 * 4;
        {
            const float w = s_W[(kb + 0) * 64 + lane];
            a0 += va.x * w; a1 += vb.x * w; a2 += vc.x * w; a3 += vd.x * w;
        }
        {
            const float w = s_W[(kb + 1) * 64 + lane];
            a0 += va.y * w; a1 += vb.y * w; a2 += vc.y * w; a3 += vd.y * w;
        }
        {
            const float w = s_W[(kb + 2) * 64 + lane];
            a0 += va.z * w; a1 += vb.z * w; a2 += vc.z * w; a3 += vd.z * w;
        }
        {
            const float w = s_W[(kb + 3) * 64 + lane];
            a0 += va.w * w; a1 += vb.w * w; a2 += vc.w * w; a3 += vd.w * w;
        }
    }
    if (lane < 32) {
        a[(n0 + 0) * 32 + f] = a0;
        a[(n0 + 1) * 32 + f] = a1;
        a[(n0 + 2) * 32 + f] = a2;
        a[(n0 + 3) * 32 + f] = a3;
    } else {
        r[(n0 + 0) * 32 + f] = a0 + cadd;
        r[(n0 + 1) * 32 + f] = a1 + cadd;
        r[(n0 + 2) * 32 + f] = a2 + cadd;
        r[(n0 + 3) * 32 + f] = a3 + cadd;
    }
}

// ---------------------------------------------------------------------------
// agg1_mlp: per dst d (one wave): h2 = relu(r[d] + sum_s a[s]) (32-wide),
// then hw[d] = h2 @ W2r, g2l[d] = h2 @ W2o + c2.
// Scalar (wave-uniform) esrc loads; half-waves process 2 edges concurrently.
// (round-13 verified form)
// ---------------------------------------------------------------------------
__global__ __launch_bounds__(256) void agg1_mlp(
    const int* __restrict__ cnt, const int* __restrict__ esrc,
    const float* __restrict__ a, const float* __restrict__ r,
    const float* __restrict__ W2r, const float* __restrict__ W2o,
    const float* __restrict__ c2,
    float* __restrict__ hw, float* __restrict__ g2l)
{
    __shared__ float s_W2[1024];   // [0..511]=W2r, [512..1023]=W2o
    for (int i = threadIdx.x; i < 1024; i += 256)
        s_W2[i] = (i < 512) ? W2r[i] : W2o[i - 512];
    __syncthreads();

    const int wave = threadIdx.x >> 6;
    const int lane = threadIdx.x & 63;
    const int epar = lane >> 5;
    const int f = lane & 31;
    const int d = blockIdx.x * 4 + wave;   // grid 5000 -> exactly 20000

    const int beg = __builtin_amdgcn_readfirstlane(d * CAP);
    const int deg = __builtin_amdgcn_readfirstlane(min(cnt[d], CAP));

    float acc = (epar == 0) ? r[d * 32 + f] : 0.f;
    int k = 0;
    #pragma unroll 4
    for (; k + 1 < deg; k += 2) {
        const int s0 = esrc[beg + k];        // scalar (wave-uniform addr)
        const int s1 = esrc[beg + k + 1];    // scalar
        const int ss = (epar == 0) ? s0 : s1;
        acc += a[ss * 32 + f];
    }
    if (k < deg) {
        const int sl = esrc[beg + k];        // scalar
        if (epar == 0) acc += a[sl * 32 + f];
    }
    acc += __shfl_xor(acc, 32);              // combine the two half-waves
    const float h2 = fmaxf(acc, 0.f);        // all lanes hold h2[f]

    // GEMV 32 -> 16 (10 real): epar==0 -> hw, epar==1 -> g2l (+c2)
    float o = (epar == 1 && f < 16) ? c2[f] : 0.f;
    #pragma unroll 8
    for (int k2 = 0; k2 < 32; ++k2) {
        const float hk = __shfl(h2, k2, 32);
        if (f < 16) o += hk * s_W2[epar * 512 + k2 * 16 + f];
    }
    if (f < 16) {
        if (epar == 0) hw[d * 16 + f] = o;
        else           g2l[d * 16 + f] = o;
    }
}

// ---------------------------------------------------------------------------
// agg2_head: per dst d (one wave = 4 edge-parallel x 16 features):
//   logits = g2l[d] + sum_s hw[s]; out[d] = log_softmax(logits)
// (round-13 verified form)
// ---------------------------------------------------------------------------
__global__ __launch_bounds__(256) void agg2_head(
    const int* __restrict__ cnt, const int* __restrict__ esrc,
    const float* __restrict__ hw, const float* __restrict__ g2l,
    float* __restrict__ out)
{
    const int wave = threadIdx.x >> 6;
    const int lane = threadIdx.x & 63;
    const int epar = lane >> 4;              // 0..3: 4 edges in parallel
    const int f = lane & 15;
    const int d = blockIdx.x * 4 + wave;     // grid 5000 -> exactly 20000

    const int beg = __builtin_amdgcn_readfirstlane(d * CAP);
    const int deg = __builtin_amdgcn_readfirstlane(min(cnt[d], CAP));

    float acc = (epar == 0) ? g2l[d * 16 + f] : 0.f;
    int k = 0;
    #pragma unroll 2
    for (; k + 3 < deg; k += 4) {
        const int s0 = esrc[beg + k];        // scalar
        const int s1 = esrc[beg + k + 1];
        const int s2 = esrc[beg + k + 2];
        const int s3 = esrc[beg + k + 3];
        const int ssA = (epar & 1) ? s1 : s0;
        const int ssB = (epar & 1) ? s3 : s2;
        const int ss = (epar & 2) ? ssB : ssA;
        acc += hw[ss * 16 + f];
    }
    const int rem = deg - k;
    if (rem > 0) { const int s0 = esrc[beg + k];
                   if (epar == 0) acc += hw[s0 * 16 + f]; }
    if (rem > 1) { const int s1 = esrc[beg + k + 1];
                   if (epar == 1) acc += hw[s1 * 16 + f]; }
    if (rem > 2) { const int s2 = esrc[beg + k + 2];
                   if (epar == 2) acc += hw[s2 * 16 + f]; }

    acc += __shfl_xor(acc, 16);
    acc += __shfl_xor(acc, 32);              // all lanes: full logit[f]

    float mv = (f < 10) ? acc : -INFINITY;
    #pragma unroll
    for (int off = 8; off > 0; off >>= 1) mv = fmaxf(mv, __shfl_xor(mv, off, 16));
    float ev = (f < 10) ? expf(acc - mv) : 0.f;
    #pragma unroll
    for (int off = 8; off > 0; off >>= 1) ev += __shfl_xor(ev, off, 16);
    const float lse = mv + logf(ev);
    if (epar == 0 && f < 10) out[d * 10 + f] = acc - lse;
}

// ---------------------------------------------------------------------------
extern "C" void kernel_launch(void* const* d_in, const int* in_sizes, int n_in,
                              void* d_out, int out_size, void* d_ws, size_t ws_size,
                              hipStream_t stream) {
    const float* x       = (const float*)d_in[0];
    const int*   ei      = (const int*)d_in[1];
    const float* w_rel1  = (const float*)d_in[2];
    const float* b_rel1  = (const float*)d_in[3];
    const float* w_root1 = (const float*)d_in[4];
    const float* w_l1    = (const float*)d_in[5];
    const float* b_l1    = (const float*)d_in[6];
    const float* w_rel2  = (const float*)d_in[7];
    const float* b_rel2  = (const float*)d_in[8];
    const float* w_root2 = (const float*)d_in[9];
    const float* w_l2    = (const float*)d_in[10];
    const float* b_l2    = (const float*)d_in[11];
    float* out = (float*)d_out;

    float* ws   = (float*)d_ws;
    float* a    = ws;                      // [20000,32]
    float* r    = ws + 640000;             // [20000,32]
    float* hw   = ws + 1280000;            // [20000,16]
    float* g2l  = ws + 1600000;            // [20000,16]
    float* P1   = ws + 1920000;            // [128,32]
    float* Q1   = ws + 1924096;            // [128,32]
    float* c1   = ws + 1928192;            // [32]
    float* W2r  = ws + 1928224;            // [32,16]
    float* W2o  = ws + 1928736;            // [32,16]
    float* c2   = ws + 1929248;            // [16]
    int* ibase  = (int*)(ws + 1929264);
    int* cnt    = ibase;                   // [20000]
    int* esrc   = ibase + 20000;           // [20000*96] = 1,920,000

    // Weight composition + cnt zeroing (one launch, disjoint blocks)
    compose_zero<<<112, 256, 0, stream>>>(w_rel1, b_rel1, w_root1, w_l1, b_l1,
                                          w_rel2, b_rel2, w_root2, w_l2, b_l2,
                                          P1, Q1, c1, W2r, W2o, c2, cnt);

    // Bucket-CSR build: 1 edge/thread, max TLP (un-fused from proj — round-13
    // fusion cost 13us via LDS-occupancy throttling)
    fill_bucket<<<2500, 256, 0, stream>>>(ei, cnt, esrc);

    // Layer-1 projections
    proj1<<<1250, 256, 0, stream>>>(x, P1, Q1, c1, a, r);

    // Aggregate + relu + folded layer-2 projections (scalar edge loads)
    agg1_mlp<<<5000, 256, 0, stream>>>(cnt, esrc, a, r, W2r, W2o, c2, hw, g2l);

    // Layer-2 aggregate + log-softmax (scalar edge loads)
    agg2_head<<<5000, 256, 0, stream>>>(cnt, esrc, hw, g2l, out);
}

// Round 15
// 169.553 us; speedup vs baseline: 1.0422x; 1.0422x over previous
//
#include <hip/hip_runtime.h>
#include <math.h>

#define N_NODES 20000
#define N_EDGES 640000
#define CAP 96        // bucket capacity: deg ~ Binom(640k,1/20k), mean 32, +11 sigma

// ---------------------------------------------------------------------------
// compose_zero: (blocks 0..32) fold post-aggregation linears into projections;
// (blocks 33..111) zero the cnt array.
// ---------------------------------------------------------------------------
__global__ __launch_bounds__(256) void compose_zero(
    const float* __restrict__ w_rel1, const float* __restrict__ b_rel1,
    const float* __restrict__ w_root1,
    const float* __restrict__ w_l1, const float* __restrict__ b_l1,
    const float* __restrict__ w_rel2, const float* __restrict__ b_rel2,
    const float* __restrict__ w_root2,
    const float* __restrict__ w_l2, const float* __restrict__ b_l2,
    float* __restrict__ P1, float* __restrict__ Q1, float* __restrict__ c1,
    float* __restrict__ W2r, float* __restrict__ W2o, float* __restrict__ c2,
    int* __restrict__ cnt)
{
    const int b = blockIdx.x, t = threadIdx.x;
    if (b < 32) {
        const bool isP = (b < 16);
        const int idx = (isP ? b : b - 16) * 256 + t;   // 0..4095
        const int k = idx >> 5, j = idx & 31;
        const float* wsrc = isP ? w_rel1 : w_root1;
        float s = 0.f;
        #pragma unroll 8
        for (int m = 0; m < 64; ++m) s += wsrc[k * 64 + m] * w_l1[m * 32 + j];
        (isP ? P1 : Q1)[idx] = s;
    } else if (b == 32) {
        for (int i = t; i < 512; i += 256) {
            const int k = i >> 4, j = i & 15;
            float sr = 0.f, so = 0.f;
            if (j < 10) {
                #pragma unroll
                for (int m = 0; m < 16; ++m) {
                    sr += w_rel2[k * 16 + m] * w_l2[m * 10 + j];
                    so += w_root2[k * 16 + m] * w_l2[m * 10 + j];
                }
            }
            W2r[i] = sr;
            W2o[i] = so;
        }
        if (t < 32) {
            float s = b_l1[t];
            #pragma unroll 8
            for (int m = 0; m < 64; ++m) s += b_rel1[m] * w_l1[m * 32 + t];
            c1[t] = s;
        }
        if (t < 16) {
            float s = 0.f;
            if (t < 10) {
                s = b_l2[t];
                #pragma unroll
                for (int m = 0; m < 16; ++m) s += b_rel2[m] * w_l2[m * 10 + t];
            }
            c2[t] = s;
        }
    } else {
        const int i = (b - 33) * 256 + t;
        if (i < N_NODES) cnt[i] = 0;
    }
}

// ---------------------------------------------------------------------------
// fill_proj2: blocks 0..1249   -> bucket-CSR fill (2 edges/thread, int2)
//             blocks 1250..1874 -> a = x @ P1      (16KB LDS)
//             blocks 1875..2499 -> r = x @ Q1 + c1 (16KB LDS)
// Fill is bound by its 41MB random-sector write-through (~46us floor; rounds
// 8/10/13/14 showed TLP/MLP don't move it) — proj hides under it. 16KB LDS
// (not 32) so occupancy is wave-limited at 8 blocks/CU, not LDS-limited at 5
// (the round-13 mistake).
// ---------------------------------------------------------------------------
__global__ __launch_bounds__(256) void fill_proj2(
    const int* __restrict__ ei, int* __restrict__ cnt, int* __restrict__ esrc,
    const float* __restrict__ x, const float* __restrict__ P1,
    const float* __restrict__ Q1, const float* __restrict__ c1,
    float* __restrict__ a, float* __restrict__ r)
{
    __shared__ float s_W[128 * 32];   // 16 KB
    const int b = blockIdx.x;
    if (b < 1250) {
        // ---- bucket CSR build: 2 edges/thread (1250*256*2 = 640000 exact) ----
        const int t = b * 256 + threadIdx.x;
        const int2 ss = ((const int2*)ei)[t];
        const int2 dd = ((const int2*)(ei + N_EDGES))[t];
        const int p0 = atomicAdd(&cnt[dd.x], 1);
        const int p1 = atomicAdd(&cnt[dd.y], 1);
        if (p0 < CAP) esrc[dd.x * CAP + p0] = ss.x;
        if (p1 < CAP) esrc[dd.y * CAP + p1] = ss.y;
    } else {
        // ---- proj: half-kernel computes a (P1), other half r (Q1 + c1) ----
        const bool isA = (b < 1875);
        const float* W = isA ? P1 : Q1;
        for (int i = threadIdx.x; i < 128 * 32; i += 256) s_W[i] = W[i];
        __syncthreads();

        const int wave = threadIdx.x >> 6;
        const int lane = threadIdx.x & 63;
        const int npar = lane >> 5;          // half-wave = one node quad
        const int f = lane & 31;
        const int base = isA ? (b - 1250) : (b - 1875);
        const int n0 = base * 32 + wave * 8 + npar * 4;   // 625*32 = 20000
        const float cadd = isA ? 0.f : c1[f];

        const float4* xp0 = (const float4*)(x + (n0 + 0) * 128);
        const float4* xp1 = (const float4*)(x + (n0 + 1) * 128);
        const float4* xp2 = (const float4*)(x + (n0 + 2) * 128);
        const float4* xp3 = (const float4*)(x + (n0 + 3) * 128);
        float o0 = 0.f, o1 = 0.f, o2 = 0.f, o3 = 0.f;
        #pragma unroll 8
        for (int k4 = 0; k4 < 32; ++k4) {
            const float4 va = xp0[k4], vb = xp1[k4], vc = xp2[k4], vd = xp3[k4];
            const int kb = k4 * 4;
            {
                const float w = s_W[(kb + 0) * 32 + f];
                o0 += va.x * w; o1 += vb.x * w; o2 += vc.x * w; o3 += vd.x * w;
            }
            {
                const float w = s_W[(kb + 1) * 32 + f];
                o0 += va.y * w; o1 += vb.y * w; o2 += vc.y * w; o3 += vd.y * w;
            }
            {
                const float w = s_W[(kb + 2) * 32 + f];
                o0 += va.z * w; o1 += vb.z * w; o2 += vc.z * w; o3 += vd.z * w;
            }
            {
                const float w = s_W[(kb + 3) * 32 + f];
                o0 += va.w * w; o1 += vb.w * w; o2 += vc.w * w; o3 += vd.w * w;
            }
        }
        float* dst = isA ? a : r;
        dst[(n0 + 0) * 32 + f] = o0 + cadd;
        dst[(n0 + 1) * 32 + f] = o1 + cadd;
        dst[(n0 + 2) * 32 + f] = o2 + cadd;
        dst[(n0 + 3) * 32 + f] = o3 + cadd;
    }
}

// ---------------------------------------------------------------------------
// agg1_mlp: per dst d (one wave): h2 = relu(r[d] + sum_s a[s]) (32-wide),
// then hw[d] = h2 @ W2r, g2l[d] = h2 @ W2o + c2.
// Scalar (wave-uniform) esrc loads; half-waves process 2 edges concurrently.
// (round-13/14 verified form)
// ---------------------------------------------------------------------------
__global__ __launch_bounds__(256) void agg1_mlp(
    const int* __restrict__ cnt, const int* __restrict__ esrc,
    const float* __restrict__ a, const float* __restrict__ r,
    const float* __restrict__ W2r, const float* __restrict__ W2o,
    const float* __restrict__ c2,
    float* __restrict__ hw, float* __restrict__ g2l)
{
    __shared__ float s_W2[1024];   // [0..511]=W2r, [512..1023]=W2o
    for (int i = threadIdx.x; i < 1024; i += 256)
        s_W2[i] = (i < 512) ? W2r[i] : W2o[i - 512];
    __syncthreads();

    const int wave = threadIdx.x >> 6;
    const int lane = threadIdx.x & 63;
    const int epar = lane >> 5;
    const int f = lane & 31;
    const int d = blockIdx.x * 4 + wave;   // grid 5000 -> exactly 20000

    const int beg = __builtin_amdgcn_readfirstlane(d * CAP);
    const int deg = __builtin_amdgcn_readfirstlane(min(cnt[d], CAP));

    float acc = (epar == 0) ? r[d * 32 + f] : 0.f;
    int k = 0;
    #pragma unroll 4
    for (; k + 1 < deg; k += 2) {
        const int s0 = esrc[beg + k];        // scalar (wave-uniform addr)
        const int s1 = esrc[beg + k + 1];    // scalar
        const int ss = (epar == 0) ? s0 : s1;
        acc += a[ss * 32 + f];
    }
    if (k < deg) {
        const int sl = esrc[beg + k];        // scalar
        if (epar == 0) acc += a[sl * 32 + f];
    }
    acc += __shfl_xor(acc, 32);              // combine the two half-waves
    const float h2 = fmaxf(acc, 0.f);        // all lanes hold h2[f]

    // GEMV 32 -> 16 (10 real): epar==0 -> hw, epar==1 -> g2l (+c2)
    float o = (epar == 1 && f < 16) ? c2[f] : 0.f;
    #pragma unroll 8
    for (int k2 = 0; k2 < 32; ++k2) {
        const float hk = __shfl(h2, k2, 32);
        if (f < 16) o += hk * s_W2[epar * 512 + k2 * 16 + f];
    }
    if (f < 16) {
        if (epar == 0) hw[d * 16 + f] = o;
        else           g2l[d * 16 + f] = o;
    }
}

// ---------------------------------------------------------------------------
// agg2_head: per dst d (one wave = 4 edge-parallel x 16 features):
//   logits = g2l[d] + sum_s hw[s]; out[d] = log_softmax(logits)
// (round-13/14 verified form)
// ---------------------------------------------------------------------------
__global__ __launch_bounds__(256) void agg2_head(
    const int* __restrict__ cnt, const int* __restrict__ esrc,
    const float* __restrict__ hw, const float* __restrict__ g2l,
    float* __restrict__ out)
{
    const int wave = threadIdx.x >> 6;
    const int lane = threadIdx.x & 63;
    const int epar = lane >> 4;              // 0..3: 4 edges in parallel
    const int f = lane & 15;
    const int d = blockIdx.x * 4 + wave;     // grid 5000 -> exactly 20000

    const int beg = __builtin_amdgcn_readfirstlane(d * CAP);
    const int deg = __builtin_amdgcn_readfirstlane(min(cnt[d], CAP));

    float acc = (epar == 0) ? g2l[d * 16 + f] : 0.f;
    int k = 0;
    #pragma unroll 2
    for (; k + 3 < deg; k += 4) {
        const int s0 = esrc[beg + k];        // scalar
        const int s1 = esrc[beg + k + 1];
        const int s2 = esrc[beg + k + 2];
        const int s3 = esrc[beg + k + 3];
        const int ssA = (epar & 1) ? s1 : s0;
        const int ssB = (epar & 1) ? s3 : s2;
        const int ss = (epar & 2) ? ssB : ssA;
        acc += hw[ss * 16 + f];
    }
    const int rem = deg - k;
    if (rem > 0) { const int s0 = esrc[beg + k];
                   if (epar == 0) acc += hw[s0 * 16 + f]; }
    if (rem > 1) { const int s1 = esrc[beg + k + 1];
                   if (epar == 1) acc += hw[s1 * 16 + f]; }
    if (rem > 2) { const int s2 = esrc[beg + k + 2];
                   if (epar == 2) acc += hw[s2 * 16 + f]; }

    acc += __shfl_xor(acc, 16);
    acc += __shfl_xor(acc, 32);              // all lanes: full logit[f]

    float mv = (f < 10) ? acc : -INFINITY;
    #pragma unroll
    for (int off = 8; off > 0; off >>= 1) mv = fmaxf(mv, __shfl_xor(mv, off, 16));
    float ev = (f < 10) ? expf(acc - mv) : 0.f;
    #pragma unroll
    for (int off = 8; off > 0; off >>= 1) ev += __shfl_xor(ev, off, 16);
    const float lse = mv + logf(ev);
    if (epar == 0 && f < 10) out[d * 10 + f] = acc - lse;
}

// ---------------------------------------------------------------------------
extern "C" void kernel_launch(void* const* d_in, const int* in_sizes, int n_in,
                              void* d_out, int out_size, void* d_ws, size_t ws_size,
                              hipStream_t stream) {
    const float* x       = (const float*)d_in[0];
    const int*   ei      = (const int*)d_in[1];
    const float* w_rel1  = (const float*)d_in[2];
    const float* b_rel1  = (const float*)d_in[3];
    const float* w_root1 = (const float*)d_in[4];
    const float* w_l1    = (const float*)d_in[5];
    const float* b_l1    = (const float*)d_in[6];
    const float* w_rel2  = (const float*)d_in[7];
    const float* b_rel2  = (const float*)d_in[8];
    const float* w_root2 = (const float*)d_in[9];
    const float* w_l2    = (const float*)d_in[10];
    const float* b_l2    = (const float*)d_in[11];
    float* out = (float*)d_out;

    float* ws   = (float*)d_ws;
    float* a    = ws;                      // [20000,32]
    float* r    = ws + 640000;             // [20000,32]
    float* hw   = ws + 1280000;            // [20000,16]
    float* g2l  = ws + 1600000;            // [20000,16]
    float* P1   = ws + 1920000;            // [128,32]
    float* Q1   = ws + 1924096;            // [128,32]
    float* c1   = ws + 1928192;            // [32]
    float* W2r  = ws + 1928224;            // [32,16]
    float* W2o  = ws + 1928736;            // [32,16]
    float* c2   = ws + 1929248;            // [16]
    int* ibase  = (int*)(ws + 1929264);
    int* cnt    = ibase;                   // [20000]
    int* esrc   = ibase + 20000;           // [20000*96] = 1,920,000

    // Weight composition + cnt zeroing (one launch, disjoint blocks)
    compose_zero<<<112, 256, 0, stream>>>(w_rel1, b_rel1, w_root1, w_l1, b_l1,
                                          w_rel2, b_rel2, w_root2, w_l2, b_l2,
                                          P1, Q1, c1, W2r, W2o, c2, cnt);

    // Bucket-CSR build overlapped with both layer-1 projections.
    // 16KB LDS -> wave-limited occupancy (8 blocks/CU), no fill throttling.
    fill_proj2<<<2500, 256, 0, stream>>>(ei, cnt, esrc, x, P1, Q1, c1, a, r);

    // Aggregate + relu + folded layer-2 projections (scalar edge loads)
    agg1_mlp<<<5000, 256, 0, stream>>>(cnt, esrc, a, r, W2r, W2o, c2, hw, g2l);

    // Layer-2 aggregate + log-softmax (scalar edge loads)
    agg2_head<<<5000, 256, 0, stream>>>(cnt, esrc, hw, g2l, out);
}